// Round 3
// baseline (709.636 us; speedup 1.0000x reference)
//
#include <hip/hip_runtime.h>

#define EMBED 1024
#define MLP   2048
#define NE    8
#define NTOK  8192                      // 4*2048 tokens
#define RMAX  (2*NTOK + NE*128)         // 17408 gathered rows max (128-pad per expert)
#define BK    64

typedef _Float16 f16x8 __attribute__((ext_vector_type(8)));
typedef _Float16 f16x4 __attribute__((ext_vector_type(4)));
typedef float    f32x4 __attribute__((ext_vector_type(4)));

// Async 16B global->LDS copy. LDS dest is wave-uniform base + lane*16 (HW
// constraint); we permute WHICH global chunk each lane fetches (XOR swizzle).
__device__ __forceinline__ void async_copy16(const void* g, void* l) {
  __builtin_amdgcn_global_load_lds(
      (const __attribute__((address_space(1))) unsigned int*)g,
      (__attribute__((address_space(3))) unsigned int*)l, 16, 0, 0);
}

// ---------------------------------------------------------------------------
// Router: one wave per token. logits = x[t] @ gate_w (fp32), top-2, weights =
// softmax over the two selected logits (== renormalized full softmax).
// ---------------------------------------------------------------------------
__global__ __launch_bounds__(256) void router_kernel(
    const float* __restrict__ x, const float* __restrict__ gw,
    int* __restrict__ sel_e, float* __restrict__ sel_w, int* __restrict__ counts)
{
  __shared__ float gwt[NE * EMBED];   // transposed gate: gwt[e][i]
  __shared__ int cnt[NE];
  int tid = threadIdx.x;
  for (int idx = tid; idx < NE * EMBED; idx += 256) {
    int i = idx >> 3, e = idx & 7;
    gwt[e * EMBED + i] = gw[idx];     // gw is [EMBED][NE]
  }
  if (tid < NE) cnt[tid] = 0;
  __syncthreads();

  int lane = tid & 63, wv = tid >> 6;
  int t = blockIdx.x * 4 + wv;
  const float4* xr = (const float4*)(x + (size_t)t * EMBED);
  const float4* gt4 = (const float4*)gwt;
  float acc[NE];
  #pragma unroll
  for (int e = 0; e < NE; ++e) acc[e] = 0.f;
  #pragma unroll
  for (int c = 0; c < 4; ++c) {
    float4 xv = xr[c * 64 + lane];
    #pragma unroll
    for (int e = 0; e < NE; ++e) {
      float4 gv = gt4[e * 256 + c * 64 + lane];
      acc[e] += xv.x * gv.x + xv.y * gv.y + xv.z * gv.z + xv.w * gv.w;
    }
  }
  #pragma unroll
  for (int off = 1; off < 64; off <<= 1) {
    #pragma unroll
    for (int e = 0; e < NE; ++e) acc[e] += __shfl_xor(acc[e], off);
  }
  if (lane == 0) {
    int e0 = 0; float l0 = acc[0];
    #pragma unroll
    for (int e = 1; e < NE; ++e) if (acc[e] > l0) { l0 = acc[e]; e0 = e; }
    int e1 = -1; float l1 = -1e30f;
    #pragma unroll
    for (int e = 0; e < NE; ++e) if (e != e0 && acc[e] > l1) { l1 = acc[e]; e1 = e; }
    float w0 = 1.f / (1.f + expf(l1 - l0));   // softmax over {l0,l1}
    sel_e[2 * t] = e0;     sel_w[2 * t] = w0;
    sel_e[2 * t + 1] = e1; sel_w[2 * t + 1] = 1.f - w0;
    atomicAdd(&cnt[e0], 1); atomicAdd(&cnt[e1], 1);
  }
  __syncthreads();
  if (tid < NE && cnt[tid]) atomicAdd(&counts[tid], cnt[tid]);
}

// ---------------------------------------------------------------------------
__global__ void offsets_kernel(const int* __restrict__ counts,
                               int* __restrict__ offs, int* __restrict__ cursor)
{
  if (threadIdx.x == 0) {
    int o = 0;
    for (int e = 0; e < NE; ++e) {
      offs[e] = o; cursor[e] = o;
      o += (counts[e] + 127) & ~127;
    }
    offs[NE] = o;
  }
}

// ---------------------------------------------------------------------------
// Assign: scatter (token, weight) into per-expert row lists + inverse map
// inv[2t+k] = row, for the non-atomic combine. Wave-aggregated atomics.
// ---------------------------------------------------------------------------
__global__ __launch_bounds__(256) void assign_kernel(
    const int* __restrict__ sel_e, const float* __restrict__ sel_w,
    int* __restrict__ cursor, int* __restrict__ rowtok, float* __restrict__ rowcoef,
    int* __restrict__ inv)
{
  int t = blockIdx.x * 256 + threadIdx.x;
  int lane = threadIdx.x & 63;
  #pragma unroll
  for (int k = 0; k < 2; ++k) {
    int e = sel_e[2 * t + k];
    float w = sel_w[2 * t + k];
    for (int xch = 0; xch < NE; ++xch) {
      unsigned long long m = __ballot(e == xch);
      if (e == xch) {
        int leader = __ffsll((unsigned long long)m) - 1;
        int base = 0;
        if (lane == leader) base = atomicAdd(&cursor[xch], (int)__popcll(m));
        base = __shfl(base, leader);
        int pos = base + (int)__popcll(m & ((1ull << lane) - 1));
        rowtok[pos] = t;
        rowcoef[pos] = w;
        inv[2 * t + k] = pos;
      }
    }
  }
}

// ---------------------------------------------------------------------------
// Gather: xg[row] = fp16(x[rowtok[row]]); zeros for padding rows (tok = -1).
// ---------------------------------------------------------------------------
__global__ __launch_bounds__(256) void gather_kernel(
    const float* __restrict__ x, const int* __restrict__ rowtok,
    _Float16* __restrict__ xg)
{
  int r = blockIdx.x;
  int tok = rowtok[r];
  int t4 = threadIdx.x * 4;
  _Float16* dst = xg + (size_t)r * EMBED + t4;
  if (tok >= 0) {
    float4 v = *(const float4*)(x + (size_t)tok * EMBED + t4);
    f16x4 h; h.x = (_Float16)v.x; h.y = (_Float16)v.y; h.z = (_Float16)v.z; h.w = (_Float16)v.w;
    *(f16x4*)dst = h;
  } else {
    f16x4 z = {(_Float16)0.f, (_Float16)0.f, (_Float16)0.f, (_Float16)0.f};
    *(f16x4*)dst = z;
  }
}

// ---------------------------------------------------------------------------
// Transpose+cast all three weight tensors in ONE launch.
// fp32 [E][K][N] -> fp16 [E][N][K]. 512 64x64 tiles per (matrix, expert).
// ---------------------------------------------------------------------------
__global__ __launch_bounds__(256) void transpose_all_kernel(
    const float* __restrict__ w1, const float* __restrict__ w3,
    const float* __restrict__ w2, _Float16* __restrict__ w1t,
    _Float16* __restrict__ w3t, _Float16* __restrict__ w2t)
{
  int id = blockIdx.x;            // 3 * 8 * 512
  int mat = id >> 12;             // 4096 blocks per matrix
  int rr = id & 4095;
  int e = rr >> 9, tile = rr & 511;
  const float* src; _Float16* dst; int K, N;
  if (mat == 0)      { src = w1; dst = w1t; K = EMBED; N = MLP; }
  else if (mat == 1) { src = w3; dst = w3t; K = EMBED; N = MLP; }
  else               { src = w2; dst = w2t; K = MLP;   N = EMBED; }
  int nx = K >> 6;
  int k0 = (tile % nx) * 64, n0 = (tile / nx) * 64;
  src += (size_t)e * K * N;
  dst += (size_t)e * K * N;

  __shared__ float tilebuf[64][65];
  int t = threadIdx.x;
  int r = t >> 4, c4 = (t & 15) * 4;
  #pragma unroll
  for (int i = 0; i < 4; ++i) {
    float4 v = *(const float4*)(src + (size_t)(k0 + r + 16 * i) * N + n0 + c4);
    tilebuf[r + 16 * i][c4 + 0] = v.x;
    tilebuf[r + 16 * i][c4 + 1] = v.y;
    tilebuf[r + 16 * i][c4 + 2] = v.z;
    tilebuf[r + 16 * i][c4 + 3] = v.w;
  }
  __syncthreads();
  int kk8 = (t & 7) * 8, nIdx = t >> 3;
  #pragma unroll
  for (int i = 0; i < 2; ++i) {
    int n = nIdx + 32 * i;
    f16x8 h;
    #pragma unroll
    for (int j = 0; j < 8; ++j) h[j] = (_Float16)tilebuf[kk8 + j][n];
    *(f16x8*)(dst + (size_t)(n0 + n) * K + k0 + kk8) = h;
  }
}

// ---------------------------------------------------------------------------
__device__ __forceinline__ int resolve_expert(const int* __restrict__ offs, int r0)
{
  int e = 0;
  #pragma unroll
  for (int q = 0; q < NE - 1; ++q) if (r0 >= offs[q + 1]) e = q + 1;
  return e;
}

// B-tile LDS geometry (BK=64): 128 rows x 64 f16 = 128 B/row = 8 chunks of
// 16 B. Physical chunk cp in row holds logical chunk cp ^ (row & 7).
// Read: logical chunk = s*4 + quad -> phys = (s*4+quad) ^ (row&7); the XOR
// spreads the 16-l16-lane row walk across all banks (128 B row = exact bank
// wrap would otherwise be a full conflict).
__device__ __forceinline__ const _Float16* bfrag_addr(const _Float16* buf, int row,
                                                      int s, int quad)
{
  return buf + row * BK + ((((s << 2) + quad) ^ (row & 7)) << 3);
}

// ---------------------------------------------------------------------------
// GEMM1 (fused SwiGLU): h = silu(xg@w1t^T) * (xg@w3t^T) * coef, fp16 out.
// 128x128 tile, BK=64. B1/B3 staged via global_load_lds (multicast in LDS);
// A fragments loaded DIRECTLY global->VGPR (k-contig 16B, L1-served) --
// cuts LDS traffic 1.5x vs staging all three operands.
// ---------------------------------------------------------------------------
__global__ __launch_bounds__(256, 2) void gemm1_kernel(
    const _Float16* __restrict__ xg, const _Float16* __restrict__ w1t,
    const _Float16* __restrict__ w3t, const float* __restrict__ rowcoef,
    const int* __restrict__ offs, _Float16* __restrict__ hb)
{
  int r0 = blockIdx.x * 128;
  if (r0 >= offs[NE]) return;
  int e = resolve_expert(offs, r0);
  int n0 = blockIdx.y * 128;
  const _Float16* B1 = w1t + (size_t)e * MLP * EMBED;
  const _Float16* B3 = w3t + (size_t)e * MLP * EMBED;

  __shared__ __align__(16) _Float16 Bs1[128 * BK];
  __shared__ __align__(16) _Float16 Bs3[128 * BK];

  int tid = threadIdx.x, lane = tid & 63, wv = tid >> 6;
  int wm = (wv & 1) << 6, wn = (wv >> 1) << 6;
  int l16 = lane & 15, quad = lane >> 4;

  const _Float16* Arow[4];
  #pragma unroll
  for (int i = 0; i < 4; ++i)
    Arow[i] = xg + (size_t)(r0 + wm + 16 * i + l16) * EMBED + quad * 8;

  f32x4 acc1[4][4], acc3[4][4];
  f32x4 z4 = {0.f, 0.f, 0.f, 0.f};
  #pragma unroll
  for (int i = 0; i < 4; ++i)
    #pragma unroll
    for (int j = 0; j < 4; ++j) { acc1[i][j] = z4; acc3[i][j] = z4; }

  for (int kk = 0; kk < EMBED; kk += BK) {
    __syncthreads();
    #pragma unroll
    for (int p = 0; p < 4; ++p) {
      int c = p * 256 + tid;                 // chunk 0..1023
      int row = c >> 3, cp = c & 7;
      int cl = cp ^ (row & 7);               // swizzled logical chunk
      size_t gof = (size_t)(n0 + row) * EMBED + kk + cl * 8;
      int lof = (p * 256 + wv * 64) * 8;     // wave-uniform LDS base (f16 units)
      async_copy16(B1 + gof, Bs1 + lof);
      async_copy16(B3 + gof, Bs3 + lof);
    }
    // A fragments for this k-block: direct global->VGPR (no barrier needed;
    // the pre-compute __syncthreads drains vmcnt for these too).
    f16x8 af[2][4];
    #pragma unroll
    for (int s = 0; s < 2; ++s)
      #pragma unroll
      for (int i = 0; i < 4; ++i)
        af[s][i] = *(const f16x8*)(Arow[i] + kk + s * 32);
    __syncthreads();
    #pragma unroll
    for (int s = 0; s < 2; ++s) {
      f16x8 b1f[4], b3f[4];
      #pragma unroll
      for (int j = 0; j < 4; ++j) {
        int row = wn + 16 * j + l16;
        b1f[j] = *(const f16x8*)bfrag_addr(Bs1, row, s, quad);
        b3f[j] = *(const f16x8*)bfrag_addr(Bs3, row, s, quad);
      }
      #pragma unroll
      for (int i = 0; i < 4; ++i)
        #pragma unroll
        for (int j = 0; j < 4; ++j) {
          acc1[i][j] = __builtin_amdgcn_mfma_f32_16x16x32_f16(af[s][i], b1f[j], acc1[i][j], 0, 0, 0);
          acc3[i][j] = __builtin_amdgcn_mfma_f32_16x16x32_f16(af[s][i], b3f[j], acc3[i][j], 0, 0, 0);
        }
    }
  }

  // Epilogue: h = silu(g)*u*coef[row]; C/D layout col=lane&15, row=quad*4+reg.
  #pragma unroll
  for (int i = 0; i < 4; ++i) {
    int mb = r0 + wm + 16 * i + quad * 4;
    float cf[4];
    #pragma unroll
    for (int rg = 0; rg < 4; ++rg) cf[rg] = rowcoef[mb + rg];
    #pragma unroll
    for (int j = 0; j < 4; ++j) {
      int col = n0 + wn + 16 * j + l16;
      #pragma unroll
      for (int rg = 0; rg < 4; ++rg) {
        float g = acc1[i][j][rg], u = acc3[i][j][rg];
        float h = g * u * cf[rg] / (1.f + __expf(-g));
        hb[(size_t)(mb + rg) * MLP + col] = (_Float16)h;
      }
    }
  }
}

// ---------------------------------------------------------------------------
// GEMM2: hb2[row] = h[row] @ w2t^T, fp16 out per ROW (no atomics; combine
// kernel sums the 2 rows per token). Same A-direct/B-LDS structure, K=2048.
// ---------------------------------------------------------------------------
__global__ __launch_bounds__(256, 2) void gemm2_kernel(
    const _Float16* __restrict__ hb, const _Float16* __restrict__ w2t,
    const int* __restrict__ offs, _Float16* __restrict__ hb2)
{
  int r0 = blockIdx.x * 128;
  if (r0 >= offs[NE]) return;
  int e = resolve_expert(offs, r0);
  int n0 = blockIdx.y * 128;
  const _Float16* B = w2t + (size_t)e * EMBED * MLP;

  __shared__ __align__(16) _Float16 Bs[128 * BK];

  int tid = threadIdx.x, lane = tid & 63, wv = tid >> 6;
  int wm = (wv & 1) << 6, wn = (wv >> 1) << 6;
  int l16 = lane & 15, quad = lane >> 4;

  const _Float16* Arow[4];
  #pragma unroll
  for (int i = 0; i < 4; ++i)
    Arow[i] = hb + (size_t)(r0 + wm + 16 * i + l16) * MLP + quad * 8;

  f32x4 acc[4][4];
  f32x4 z4 = {0.f, 0.f, 0.f, 0.f};
  #pragma unroll
  for (int i = 0; i < 4; ++i)
    #pragma unroll
    for (int j = 0; j < 4; ++j) acc[i][j] = z4;

  for (int kk = 0; kk < MLP; kk += BK) {
    __syncthreads();
    #pragma unroll
    for (int p = 0; p < 4; ++p) {
      int c = p * 256 + tid;
      int row = c >> 3, cp = c & 7;
      int cl = cp ^ (row & 7);
      size_t gof = (size_t)(n0 + row) * MLP + kk + cl * 8;
      int lof = (p * 256 + wv * 64) * 8;
      async_copy16(B + gof, Bs + lof);
    }
    f16x8 af[2][4];
    #pragma unroll
    for (int s = 0; s < 2; ++s)
      #pragma unroll
      for (int i = 0; i < 4; ++i)
        af[s][i] = *(const f16x8*)(Arow[i] + kk + s * 32);
    __syncthreads();
    #pragma unroll
    for (int s = 0; s < 2; ++s) {
      f16x8 bf[4];
      #pragma unroll
      for (int j = 0; j < 4; ++j)
        bf[j] = *(const f16x8*)bfrag_addr(Bs, wn + 16 * j + l16, s, quad);
      #pragma unroll
      for (int i = 0; i < 4; ++i)
        #pragma unroll
        for (int j = 0; j < 4; ++j)
          acc[i][j] = __builtin_amdgcn_mfma_f32_16x16x32_f16(af[s][i], bf[j], acc[i][j], 0, 0, 0);
    }
  }

  #pragma unroll
  for (int i = 0; i < 4; ++i) {
    int mb = r0 + wm + 16 * i + quad * 4;
    #pragma unroll
    for (int j = 0; j < 4; ++j) {
      int col = n0 + wn + 16 * j + l16;
      #pragma unroll
      for (int rg = 0; rg < 4; ++rg)
        hb2[(size_t)(mb + rg) * EMBED + col] = (_Float16)acc[i][j][rg];
    }
  }
}

// ---------------------------------------------------------------------------
// Combine: out[t] = hb2[inv[2t]] + hb2[inv[2t+1]] (fp32 out).
// ---------------------------------------------------------------------------
__global__ __launch_bounds__(256) void combine_kernel(
    const _Float16* __restrict__ hb2, const int* __restrict__ inv,
    float* __restrict__ out)
{
  int t = blockIdx.x;
  int d = threadIdx.x * 4;
  int p0 = inv[2 * t], p1 = inv[2 * t + 1];
  f16x4 a = *(const f16x4*)(hb2 + (size_t)p0 * EMBED + d);
  f16x4 b = *(const f16x4*)(hb2 + (size_t)p1 * EMBED + d);
  float4 r;
  r.x = (float)a.x + (float)b.x;
  r.y = (float)a.y + (float)b.y;
  r.z = (float)a.z + (float)b.z;
  r.w = (float)a.w + (float)b.w;
  *(float4*)(out + (size_t)t * EMBED + d) = r;
}

// ---------------------------------------------------------------------------
extern "C" void kernel_launch(void* const* d_in, const int* in_sizes, int n_in,
                              void* d_out, int out_size, void* d_ws, size_t ws_size,
                              hipStream_t stream)
{
  (void)in_sizes; (void)n_in; (void)ws_size; (void)out_size;
  const float* x  = (const float*)d_in[0];
  const float* gw = (const float*)d_in[1];
  const float* w1 = (const float*)d_in[2];
  const float* w2 = (const float*)d_in[3];   // NOTE: dict order is w1, w2, w3
  const float* w3 = (const float*)d_in[4];
  float* out = (float*)d_out;
  char* ws = (char*)d_ws;

  size_t o = 0;
  auto alloc = [&](size_t bytes) { size_t r = o; o = (o + bytes + 255) & ~255ULL; return r; };
  const size_t wbytes = (size_t)NE * MLP * EMBED * 2;
  _Float16* w1t = (_Float16*)(ws + alloc(wbytes));
  _Float16* w3t = (_Float16*)(ws + alloc(wbytes));
  _Float16* w2t = (_Float16*)(ws + alloc(wbytes));
  _Float16* xg  = (_Float16*)(ws + alloc((size_t)RMAX * EMBED * 2));
  _Float16* hb  = (_Float16*)(ws + alloc((size_t)RMAX * MLP * 2));
  int*   rowtok  = (int*)(ws + alloc((size_t)RMAX * 4));
  float* rowcoef = (float*)(ws + alloc((size_t)RMAX * 4));
  int*   sel_e   = (int*)(ws + alloc((size_t)2 * NTOK * 4));
  float* sel_w   = (float*)(ws + alloc((size_t)2 * NTOK * 4));
  int*   inv     = (int*)(ws + alloc((size_t)2 * NTOK * 4));
  int*   meta    = (int*)(ws + alloc(256));
  int* counts = meta;          // [8]
  int* offs   = meta + 8;      // [9]
  int* cursor = meta + 17;     // [8]
  // hb2 aliases xg: xg is dead after gemm1; both are RMAX*EMBED fp16.
  _Float16* hb2 = xg;

  hipMemsetAsync(meta, 0, 256, stream);
  hipMemsetAsync(rowtok, 0xFF, (size_t)RMAX * 4, stream);   // -1 = padding
  hipMemsetAsync(rowcoef, 0, (size_t)RMAX * 4, stream);

  transpose_all_kernel<<<3 * 4096, 256, 0, stream>>>(w1, w3, w2, w1t, w3t, w2t);

  router_kernel<<<NTOK / 4, 256, 0, stream>>>(x, gw, sel_e, sel_w, counts);
  offsets_kernel<<<1, 64, 0, stream>>>(counts, offs, cursor);
  assign_kernel<<<NTOK / 256, 256, 0, stream>>>(sel_e, sel_w, cursor, rowtok, rowcoef, inv);
  gather_kernel<<<RMAX, 256, 0, stream>>>(x, rowtok, xg);

  gemm1_kernel<<<dim3(RMAX / 128, MLP / 128), 256, 0, stream>>>(xg, w1t, w3t, rowcoef, offs, hb);
  gemm2_kernel<<<dim3(RMAX / 128, EMBED / 128), 256, 0, stream>>>(hb, w2t, offs, hb2);
  combine_kernel<<<NTOK, 256, 0, stream>>>(hb2, inv, out);
}

// Round 4
// 637.184 us; speedup vs baseline: 1.1137x; 1.1137x over previous
//
#include <hip/hip_runtime.h>

#define EMBED 1024
#define MLP   2048
#define NE    8
#define NTOK  8192                      // 4*2048 tokens
#define RMAX  (2*NTOK + NE*128)         // 17408 gathered rows max (128-pad per expert)

typedef _Float16 f16x8 __attribute__((ext_vector_type(8)));
typedef _Float16 f16x4 __attribute__((ext_vector_type(4)));
typedef float    f32x4 __attribute__((ext_vector_type(4)));

// Async 16B global->LDS copy. LDS dest is wave-uniform base + lane*16 (HW
// constraint); we permute WHICH global chunk each lane fetches (XOR swizzle).
__device__ __forceinline__ void async_copy16(const void* g, void* l) {
  __builtin_amdgcn_global_load_lds(
      (const __attribute__((address_space(1))) unsigned int*)g,
      (__attribute__((address_space(3))) unsigned int*)l, 16, 0, 0);
}

// ---------------------------------------------------------------------------
// Router: one wave per token. logits = x[t] @ gate_w (fp32), top-2, weights =
// softmax over the two selected logits (== renormalized full softmax).
// ---------------------------------------------------------------------------
__global__ __launch_bounds__(256) void router_kernel(
    const float* __restrict__ x, const float* __restrict__ gw,
    int* __restrict__ sel_e, float* __restrict__ sel_w, int* __restrict__ counts)
{
  __shared__ float gwt[NE * EMBED];   // transposed gate: gwt[e][i]
  __shared__ int cnt[NE];
  int tid = threadIdx.x;
  for (int idx = tid; idx < NE * EMBED; idx += 256) {
    int i = idx >> 3, e = idx & 7;
    gwt[e * EMBED + i] = gw[idx];     // gw is [EMBED][NE]
  }
  if (tid < NE) cnt[tid] = 0;
  __syncthreads();

  int lane = tid & 63, wv = tid >> 6;
  int t = blockIdx.x * 4 + wv;
  const float4* xr = (const float4*)(x + (size_t)t * EMBED);
  const float4* gt4 = (const float4*)gwt;
  float acc[NE];
  #pragma unroll
  for (int e = 0; e < NE; ++e) acc[e] = 0.f;
  #pragma unroll
  for (int c = 0; c < 4; ++c) {
    float4 xv = xr[c * 64 + lane];
    #pragma unroll
    for (int e = 0; e < NE; ++e) {
      float4 gv = gt4[e * 256 + c * 64 + lane];
      acc[e] += xv.x * gv.x + xv.y * gv.y + xv.z * gv.z + xv.w * gv.w;
    }
  }
  #pragma unroll
  for (int off = 1; off < 64; off <<= 1) {
    #pragma unroll
    for (int e = 0; e < NE; ++e) acc[e] += __shfl_xor(acc[e], off);
  }
  if (lane == 0) {
    int e0 = 0; float l0 = acc[0];
    #pragma unroll
    for (int e = 1; e < NE; ++e) if (acc[e] > l0) { l0 = acc[e]; e0 = e; }
    int e1 = -1; float l1 = -1e30f;
    #pragma unroll
    for (int e = 0; e < NE; ++e) if (e != e0 && acc[e] > l1) { l1 = acc[e]; e1 = e; }
    float w0 = 1.f / (1.f + expf(l1 - l0));   // softmax over {l0,l1}
    sel_e[2 * t] = e0;     sel_w[2 * t] = w0;
    sel_e[2 * t + 1] = e1; sel_w[2 * t + 1] = 1.f - w0;
    atomicAdd(&cnt[e0], 1); atomicAdd(&cnt[e1], 1);
  }
  __syncthreads();
  if (tid < NE && cnt[tid]) atomicAdd(&counts[tid], cnt[tid]);
}

// ---------------------------------------------------------------------------
// Assign: scatter (token, weight) into per-expert row lists + inverse map.
// Each thread recomputes the 128-aligned segment offsets locally from counts
// (removes the offsets_kernel launch); block 0 publishes offs for the gemms.
// cursor is zero-based within each segment. Wave-aggregated atomics.
// ---------------------------------------------------------------------------
__global__ __launch_bounds__(256) void assign_kernel(
    const int* __restrict__ sel_e, const float* __restrict__ sel_w,
    const int* __restrict__ counts, int* __restrict__ cursor,
    int* __restrict__ offs_out, int* __restrict__ rowtok,
    float* __restrict__ rowcoef, int* __restrict__ inv)
{
  int offl[NE];
  {
    int o = 0;
    #pragma unroll
    for (int e = 0; e < NE; ++e) { offl[e] = o; o += (counts[e] + 127) & ~127; }
    if (blockIdx.x == 0 && threadIdx.x == 0) {
      #pragma unroll
      for (int e = 0; e < NE; ++e) offs_out[e] = offl[e];
      offs_out[NE] = o;
    }
  }
  int t = blockIdx.x * 256 + threadIdx.x;
  int lane = threadIdx.x & 63;
  #pragma unroll
  for (int k = 0; k < 2; ++k) {
    int e = sel_e[2 * t + k];
    float w = sel_w[2 * t + k];
    for (int xch = 0; xch < NE; ++xch) {
      unsigned long long m = __ballot(e == xch);
      if (e == xch) {
        int leader = __ffsll((unsigned long long)m) - 1;
        int base = 0;
        if (lane == leader) base = atomicAdd(&cursor[xch], (int)__popcll(m));
        base = __shfl(base, leader);
        int pos = offl[xch] + base + (int)__popcll(m & ((1ull << lane) - 1));
        rowtok[pos] = t;
        rowcoef[pos] = w;
        inv[2 * t + k] = pos;
      }
    }
  }
}

// ---------------------------------------------------------------------------
// Gather: xg[row] = fp16(x[rowtok[row]]); zeros for padding rows (tok = -1).
// ---------------------------------------------------------------------------
__global__ __launch_bounds__(256) void gather_kernel(
    const float* __restrict__ x, const int* __restrict__ rowtok,
    _Float16* __restrict__ xg)
{
  int r = blockIdx.x;
  int tok = rowtok[r];
  int t4 = threadIdx.x * 4;
  _Float16* dst = xg + (size_t)r * EMBED + t4;
  if (tok >= 0) {
    float4 v = *(const float4*)(x + (size_t)tok * EMBED + t4);
    f16x4 h; h.x = (_Float16)v.x; h.y = (_Float16)v.y; h.z = (_Float16)v.z; h.w = (_Float16)v.w;
    *(f16x4*)dst = h;
  } else {
    f16x4 z = {(_Float16)0.f, (_Float16)0.f, (_Float16)0.f, (_Float16)0.f};
    *(f16x4*)dst = z;
  }
}

// ---------------------------------------------------------------------------
// Transpose+cast all three weight tensors in ONE launch.
// fp32 [E][K][N] -> fp16 [E][N][K]. 512 64x64 tiles per (matrix, expert).
// ---------------------------------------------------------------------------
__global__ __launch_bounds__(256) void transpose_all_kernel(
    const float* __restrict__ w1, const float* __restrict__ w3,
    const float* __restrict__ w2, _Float16* __restrict__ w1t,
    _Float16* __restrict__ w3t, _Float16* __restrict__ w2t)
{
  int id = blockIdx.x;            // 3 * 8 * 512
  int mat = id >> 12;             // 4096 blocks per matrix
  int rr = id & 4095;
  int e = rr >> 9, tile = rr & 511;
  const float* src; _Float16* dst; int K, N;
  if (mat == 0)      { src = w1; dst = w1t; K = EMBED; N = MLP; }
  else if (mat == 1) { src = w3; dst = w3t; K = EMBED; N = MLP; }
  else               { src = w2; dst = w2t; K = MLP;   N = EMBED; }
  int nx = K >> 6;
  int k0 = (tile % nx) * 64, n0 = (tile / nx) * 64;
  src += (size_t)e * K * N;
  dst += (size_t)e * K * N;

  __shared__ float tilebuf[64][65];
  int t = threadIdx.x;
  int r = t >> 4, c4 = (t & 15) * 4;
  #pragma unroll
  for (int i = 0; i < 4; ++i) {
    float4 v = *(const float4*)(src + (size_t)(k0 + r + 16 * i) * N + n0 + c4);
    tilebuf[r + 16 * i][c4 + 0] = v.x;
    tilebuf[r + 16 * i][c4 + 1] = v.y;
    tilebuf[r + 16 * i][c4 + 2] = v.z;
    tilebuf[r + 16 * i][c4 + 3] = v.w;
  }
  __syncthreads();
  int kk8 = (t & 7) * 8, nIdx = t >> 3;
  #pragma unroll
  for (int i = 0; i < 2; ++i) {
    int n = nIdx + 32 * i;
    f16x8 h;
    #pragma unroll
    for (int j = 0; j < 8; ++j) h[j] = (_Float16)tilebuf[kk8 + j][n];
    *(f16x8*)(dst + (size_t)(n0 + n) * K + k0 + kk8) = h;
  }
}

// ---------------------------------------------------------------------------
__device__ __forceinline__ int resolve_expert(const int* __restrict__ offs, int r0)
{
  int e = 0;
  #pragma unroll
  for (int q = 0; q < NE - 1; ++q) if (r0 >= offs[q + 1]) e = q + 1;
  return e;
}

// BK=32 tile: 128 rows x 32 f16 (64 B/row) = 512 chunks of 16 B.
// Physical slot (row, kqp) holds logical k-quarter kql = kqp ^ ((row>>1)&3)
// (round-2-verified: 0 bank conflicts). Read: phys = quad ^ ((row>>1)&3).
__device__ __forceinline__ const _Float16* frag_addr(const _Float16* buf, int row, int quad)
{
  return buf + row * 32 + ((quad ^ ((row >> 1) & 3)) << 3);
}

// ---------------------------------------------------------------------------
// GEMM1 (fused SwiGLU): h = silu(xg@w1t^T) * (xg@w3t^T) * coef, fp16 out.
// 128x128 tile, BK=32, TRIPLE-buffered LDS with raw s_barrier + manual
// s_waitcnt vmcnt(N): stage(k+1) stays in flight across the barrier while
// buf k is computed (the AITER-style K-loop the 2-barrier form can't express).
// Race-freedom: stage(k+1) overwrites buf (k+1)%3 = buf (k-2)%3, last read at
// compute(k-2), which precedes barrier(k-1) in program order; every wave
// issuing stage(k+1) has passed barrier(k-1). Wave skew <= 1 barrier. The
// asm memory clobbers keep the compiler from hoisting epilogue loads into
// the loop (which would corrupt the vmcnt accounting).
// ---------------------------------------------------------------------------
__global__ __launch_bounds__(256, 2) void gemm1_kernel(
    const _Float16* __restrict__ xg, const _Float16* __restrict__ w1t,
    const _Float16* __restrict__ w3t, const float* __restrict__ rowcoef,
    const int* __restrict__ offs, _Float16* __restrict__ hb)
{
  int r0 = blockIdx.x * 128;
  if (r0 >= offs[NE]) return;
  int e = resolve_expert(offs, r0);
  int n0 = blockIdx.y * 128;
  const _Float16* B1 = w1t + (size_t)e * MLP * EMBED;
  const _Float16* B3 = w3t + (size_t)e * MLP * EMBED;

  __shared__ __align__(16) _Float16 As[3][128 * 32];
  __shared__ __align__(16) _Float16 Bs1[3][128 * 32];
  __shared__ __align__(16) _Float16 Bs3[3][128 * 32];

  int tid = threadIdx.x, lane = tid & 63, wv = tid >> 6;
  int wm = (wv & 1) << 6, wn = (wv >> 1) << 6;
  int l16 = lane & 15, quad = lane >> 4;

  // Per-thread staging constants: chunk c = p*256+tid -> (row, phys quarter).
  int row0 = tid >> 2,        kqp0 = tid & 3;
  int row1 = (256 + tid) >> 2, kqp1 = tid & 3;
  int kql0 = kqp0 ^ ((row0 >> 1) & 3);
  int kql1 = kqp1 ^ ((row1 >> 1) & 3);
  size_t gA0 = (size_t)(r0 + row0) * EMBED + kql0 * 8;
  size_t gA1 = (size_t)(r0 + row1) * EMBED + kql1 * 8;
  size_t gB0 = (size_t)(n0 + row0) * EMBED + kql0 * 8;
  size_t gB1 = (size_t)(n0 + row1) * EMBED + kql1 * 8;
  int lof0 = (wv * 64) * 8;          // p=0 wave-uniform LDS base (f16 units)
  int lof1 = (256 + wv * 64) * 8;    // p=1

  f32x4 acc1[4][4], acc3[4][4];
  f32x4 z4 = {0.f, 0.f, 0.f, 0.f};
  #pragma unroll
  for (int i = 0; i < 4; ++i)
    #pragma unroll
    for (int j = 0; j < 4; ++j) { acc1[i][j] = z4; acc3[i][j] = z4; }

  auto stage = [&](int b, int kk) {
    async_copy16(xg + gA0 + kk, &As[b][lof0]);
    async_copy16(B1 + gB0 + kk, &Bs1[b][lof0]);
    async_copy16(B3 + gB0 + kk, &Bs3[b][lof0]);
    async_copy16(xg + gA1 + kk, &As[b][lof1]);
    async_copy16(B1 + gB1 + kk, &Bs1[b][lof1]);
    async_copy16(B3 + gB1 + kk, &Bs3[b][lof1]);
  };

  const int NIT = EMBED / 32;        // 32 iters
  stage(0, 0);
  for (int k = 0; k < NIT; ++k) {
    int b = k % 3;
    if (k + 1 < NIT) {
      stage((k + 1) % 3, (k + 1) * 32);
      asm volatile("s_waitcnt vmcnt(6)" ::: "memory");   // stage(k) drained
    } else {
      asm volatile("s_waitcnt vmcnt(0)" ::: "memory");
    }
    asm volatile("s_barrier" ::: "memory");

    f16x8 af[4], b1f[4], b3f[4];
    #pragma unroll
    for (int i = 0; i < 4; ++i)
      af[i] = *(const f16x8*)frag_addr(As[b], wm + 16 * i + l16, quad);
    #pragma unroll
    for (int j = 0; j < 4; ++j) {
      b1f[j] = *(const f16x8*)frag_addr(Bs1[b], wn + 16 * j + l16, quad);
      b3f[j] = *(const f16x8*)frag_addr(Bs3[b], wn + 16 * j + l16, quad);
    }
    #pragma unroll
    for (int i = 0; i < 4; ++i)
      #pragma unroll
      for (int j = 0; j < 4; ++j) {
        acc1[i][j] = __builtin_amdgcn_mfma_f32_16x16x32_f16(af[i], b1f[j], acc1[i][j], 0, 0, 0);
        acc3[i][j] = __builtin_amdgcn_mfma_f32_16x16x32_f16(af[i], b3f[j], acc3[i][j], 0, 0, 0);
      }
  }

  // Epilogue: h = silu(g)*u*coef[row]; C/D layout col=lane&15, row=quad*4+reg.
  #pragma unroll
  for (int i = 0; i < 4; ++i) {
    int mb = r0 + wm + 16 * i + quad * 4;
    float cf[4];
    #pragma unroll
    for (int rg = 0; rg < 4; ++rg) cf[rg] = rowcoef[mb + rg];
    #pragma unroll
    for (int j = 0; j < 4; ++j) {
      int col = n0 + wn + 16 * j + l16;
      #pragma unroll
      for (int rg = 0; rg < 4; ++rg) {
        float g = acc1[i][j][rg], u = acc3[i][j][rg];
        float h = g * u * cf[rg] / (1.f + __expf(-g));
        hb[(size_t)(mb + rg) * MLP + col] = (_Float16)h;
      }
    }
  }
}

// ---------------------------------------------------------------------------
// GEMM2: hb2[row] = h[row] @ w2t^T, fp16 per-row out (no atomics; combine
// sums the 2 rows per token). Same triple-buffered raw-barrier K-loop.
// ---------------------------------------------------------------------------
__global__ __launch_bounds__(256, 2) void gemm2_kernel(
    const _Float16* __restrict__ hb, const _Float16* __restrict__ w2t,
    const int* __restrict__ offs, _Float16* __restrict__ hb2)
{
  int r0 = blockIdx.x * 128;
  if (r0 >= offs[NE]) return;
  int e = resolve_expert(offs, r0);
  int n0 = blockIdx.y * 128;
  const _Float16* B = w2t + (size_t)e * EMBED * MLP;

  __shared__ __align__(16) _Float16 As[3][128 * 32];
  __shared__ __align__(16) _Float16 Bs[3][128 * 32];

  int tid = threadIdx.x, lane = tid & 63, wv = tid >> 6;
  int wm = (wv & 1) << 6, wn = (wv >> 1) << 6;
  int l16 = lane & 15, quad = lane >> 4;

  int row0 = tid >> 2,        kqp0 = tid & 3;
  int row1 = (256 + tid) >> 2, kqp1 = tid & 3;
  int kql0 = kqp0 ^ ((row0 >> 1) & 3);
  int kql1 = kqp1 ^ ((row1 >> 1) & 3);
  size_t gA0 = (size_t)(r0 + row0) * MLP + kql0 * 8;
  size_t gA1 = (size_t)(r0 + row1) * MLP + kql1 * 8;
  size_t gB0 = (size_t)(n0 + row0) * MLP + kql0 * 8;
  size_t gB1 = (size_t)(n0 + row1) * MLP + kql1 * 8;
  int lof0 = (wv * 64) * 8;
  int lof1 = (256 + wv * 64) * 8;

  f32x4 acc[4][4];
  f32x4 z4 = {0.f, 0.f, 0.f, 0.f};
  #pragma unroll
  for (int i = 0; i < 4; ++i)
    #pragma unroll
    for (int j = 0; j < 4; ++j) acc[i][j] = z4;

  auto stage = [&](int b, int kk) {
    async_copy16(hb + gA0 + kk, &As[b][lof0]);
    async_copy16(B  + gB0 + kk, &Bs[b][lof0]);
    async_copy16(hb + gA1 + kk, &As[b][lof1]);
    async_copy16(B  + gB1 + kk, &Bs[b][lof1]);
  };

  const int NIT = MLP / 32;          // 64 iters
  stage(0, 0);
  for (int k = 0; k < NIT; ++k) {
    int b = k % 3;
    if (k + 1 < NIT) {
      stage((k + 1) % 3, (k + 1) * 32);
      asm volatile("s_waitcnt vmcnt(4)" ::: "memory");
    } else {
      asm volatile("s_waitcnt vmcnt(0)" ::: "memory");
    }
    asm volatile("s_barrier" ::: "memory");

    f16x8 af[4], bf[4];
    #pragma unroll
    for (int i = 0; i < 4; ++i)
      af[i] = *(const f16x8*)frag_addr(As[b], wm + 16 * i + l16, quad);
    #pragma unroll
    for (int j = 0; j < 4; ++j)
      bf[j] = *(const f16x8*)frag_addr(Bs[b], wn + 16 * j + l16, quad);
    #pragma unroll
    for (int i = 0; i < 4; ++i)
      #pragma unroll
      for (int j = 0; j < 4; ++j)
        acc[i][j] = __builtin_amdgcn_mfma_f32_16x16x32_f16(af[i], bf[j], acc[i][j], 0, 0, 0);
  }

  #pragma unroll
  for (int i = 0; i < 4; ++i) {
    int mb = r0 + wm + 16 * i + quad * 4;
    #pragma unroll
    for (int j = 0; j < 4; ++j) {
      int col = n0 + wn + 16 * j + l16;
      #pragma unroll
      for (int rg = 0; rg < 4; ++rg)
        hb2[(size_t)(mb + rg) * EMBED + col] = (_Float16)acc[i][j][rg];
    }
  }
}

// ---------------------------------------------------------------------------
// Combine: out[t] = hb2[inv[2t]] + hb2[inv[2t+1]] (fp32 out).
// ---------------------------------------------------------------------------
__global__ __launch_bounds__(256) void combine_kernel(
    const _Float16* __restrict__ hb2, const int* __restrict__ inv,
    float* __restrict__ out)
{
  int t = blockIdx.x;
  int d = threadIdx.x * 4;
  int p0 = inv[2 * t], p1 = inv[2 * t + 1];
  f16x4 a = *(const f16x4*)(hb2 + (size_t)p0 * EMBED + d);
  f16x4 b = *(const f16x4*)(hb2 + (size_t)p1 * EMBED + d);
  float4 r;
  r.x = (float)a.x + (float)b.x;
  r.y = (float)a.y + (float)b.y;
  r.z = (float)a.z + (float)b.z;
  r.w = (float)a.w + (float)b.w;
  *(float4*)(out + (size_t)t * EMBED + d) = r;
}

// ---------------------------------------------------------------------------
extern "C" void kernel_launch(void* const* d_in, const int* in_sizes, int n_in,
                              void* d_out, int out_size, void* d_ws, size_t ws_size,
                              hipStream_t stream)
{
  (void)in_sizes; (void)n_in; (void)ws_size; (void)out_size;
  const float* x  = (const float*)d_in[0];
  const float* gw = (const float*)d_in[1];
  const float* w1 = (const float*)d_in[2];
  const float* w2 = (const float*)d_in[3];   // NOTE: dict order is w1, w2, w3
  const float* w3 = (const float*)d_in[4];
  float* out = (float*)d_out;
  char* ws = (char*)d_ws;

  size_t o = 0;
  auto alloc = [&](size_t bytes) { size_t r = o; o = (o + bytes + 255) & ~255ULL; return r; };
  const size_t wbytes = (size_t)NE * MLP * EMBED * 2;
  _Float16* w1t = (_Float16*)(ws + alloc(wbytes));
  _Float16* w3t = (_Float16*)(ws + alloc(wbytes));
  _Float16* w2t = (_Float16*)(ws + alloc(wbytes));
  _Float16* xg  = (_Float16*)(ws + alloc((size_t)RMAX * EMBED * 2));
  _Float16* hb  = (_Float16*)(ws + alloc((size_t)RMAX * MLP * 2));
  int*   rowtok  = (int*)(ws + alloc((size_t)RMAX * 4));
  float* rowcoef = (float*)(ws + alloc((size_t)RMAX * 4));
  int*   sel_e   = (int*)(ws + alloc((size_t)2 * NTOK * 4));
  float* sel_w   = (float*)(ws + alloc((size_t)2 * NTOK * 4));
  int*   inv     = (int*)(ws + alloc((size_t)2 * NTOK * 4));
  int*   meta    = (int*)(ws + alloc(256));
  int* counts = meta;          // [8]
  int* offs   = meta + 8;      // [9]
  int* cursor = meta + 17;     // [8] (zero-based)
  // hb2 aliases xg: xg is dead after gemm1; both are RMAX*EMBED fp16.
  _Float16* hb2 = xg;

  hipMemsetAsync(meta, 0, 256, stream);
  hipMemsetAsync(rowtok, 0xFF, (size_t)RMAX * 4, stream);   // -1 = padding
  hipMemsetAsync(rowcoef, 0, (size_t)RMAX * 4, stream);

  transpose_all_kernel<<<3 * 4096, 256, 0, stream>>>(w1, w3, w2, w1t, w3t, w2t);

  router_kernel<<<NTOK / 4, 256, 0, stream>>>(x, gw, sel_e, sel_w, counts);
  assign_kernel<<<NTOK / 256, 256, 0, stream>>>(sel_e, sel_w, counts, cursor,
                                                offs, rowtok, rowcoef, inv);
  gather_kernel<<<RMAX, 256, 0, stream>>>(x, rowtok, xg);

  gemm1_kernel<<<dim3(RMAX / 128, MLP / 128), 256, 0, stream>>>(xg, w1t, w3t, rowcoef, offs, hb);
  gemm2_kernel<<<dim3(RMAX / 128, EMBED / 128), 256, 0, stream>>>(hb, w2t, offs, hb2);
  combine_kernel<<<NTOK, 256, 0, stream>>>(hb2, inv, out);
}

// Round 5
// 626.190 us; speedup vs baseline: 1.1333x; 1.0176x over previous
//
#include <hip/hip_runtime.h>

#define EMBED 1024
#define MLP   2048
#define NE    8
#define NTOK  8192                      // 4*2048 tokens
#define RMAX  (2*NTOK + NE*256)         // 18432 rows max (256-pad per expert)

typedef _Float16 f16x8 __attribute__((ext_vector_type(8)));
typedef _Float16 f16x4 __attribute__((ext_vector_type(4)));
typedef float    f32x4 __attribute__((ext_vector_type(4)));

// Async 16B global->LDS copy. LDS dest is wave-uniform base + lane*16 (HW
// constraint); we permute WHICH global chunk each lane fetches (XOR swizzle).
__device__ __forceinline__ void async_copy16(const void* g, void* l) {
  __builtin_amdgcn_global_load_lds(
      (const __attribute__((address_space(1))) unsigned int*)g,
      (__attribute__((address_space(3))) unsigned int*)l, 16, 0, 0);
}

// ---------------------------------------------------------------------------
// Router: one wave per token. logits = x[t] @ gate_w (fp32), top-2, weights =
// softmax over the two selected logits (== renormalized full softmax).
// ---------------------------------------------------------------------------
__global__ __launch_bounds__(256) void router_kernel(
    const float* __restrict__ x, const float* __restrict__ gw,
    int* __restrict__ sel_e, float* __restrict__ sel_w, int* __restrict__ counts)
{
  __shared__ float gwt[NE * EMBED];   // transposed gate: gwt[e][i]
  __shared__ int cnt[NE];
  int tid = threadIdx.x;
  for (int idx = tid; idx < NE * EMBED; idx += 256) {
    int i = idx >> 3, e = idx & 7;
    gwt[e * EMBED + i] = gw[idx];     // gw is [EMBED][NE]
  }
  if (tid < NE) cnt[tid] = 0;
  __syncthreads();

  int lane = tid & 63, wv = tid >> 6;
  int t = blockIdx.x * 4 + wv;
  const float4* xr = (const float4*)(x + (size_t)t * EMBED);
  const float4* gt4 = (const float4*)gwt;
  float acc[NE];
  #pragma unroll
  for (int e = 0; e < NE; ++e) acc[e] = 0.f;
  #pragma unroll
  for (int c = 0; c < 4; ++c) {
    float4 xv = xr[c * 64 + lane];
    #pragma unroll
    for (int e = 0; e < NE; ++e) {
      float4 gv = gt4[e * 256 + c * 64 + lane];
      acc[e] += xv.x * gv.x + xv.y * gv.y + xv.z * gv.z + xv.w * gv.w;
    }
  }
  #pragma unroll
  for (int off = 1; off < 64; off <<= 1) {
    #pragma unroll
    for (int e = 0; e < NE; ++e) acc[e] += __shfl_xor(acc[e], off);
  }
  if (lane == 0) {
    int e0 = 0; float l0 = acc[0];
    #pragma unroll
    for (int e = 1; e < NE; ++e) if (acc[e] > l0) { l0 = acc[e]; e0 = e; }
    int e1 = -1; float l1 = -1e30f;
    #pragma unroll
    for (int e = 0; e < NE; ++e) if (e != e0 && acc[e] > l1) { l1 = acc[e]; e1 = e; }
    float w0 = 1.f / (1.f + expf(l1 - l0));   // softmax over {l0,l1}
    sel_e[2 * t] = e0;     sel_w[2 * t] = w0;
    sel_e[2 * t + 1] = e1; sel_w[2 * t + 1] = 1.f - w0;
    atomicAdd(&cnt[e0], 1); atomicAdd(&cnt[e1], 1);
  }
  __syncthreads();
  if (tid < NE && cnt[tid]) atomicAdd(&counts[tid], cnt[tid]);
}

// ---------------------------------------------------------------------------
// Assign: scatter (token, weight) into per-expert row lists + inverse map.
// Segment starts are 256-aligned (so a 256-row GEMM tile never straddles
// experts). Block 0 publishes offs; cursor is zero-based per segment.
// ---------------------------------------------------------------------------
__global__ __launch_bounds__(256) void assign_kernel(
    const int* __restrict__ sel_e, const float* __restrict__ sel_w,
    const int* __restrict__ counts, int* __restrict__ cursor,
    int* __restrict__ offs_out, int* __restrict__ rowtok,
    float* __restrict__ rowcoef, int* __restrict__ inv)
{
  int offl[NE];
  {
    int o = 0;
    #pragma unroll
    for (int e = 0; e < NE; ++e) { offl[e] = o; o += (counts[e] + 255) & ~255; }
    if (blockIdx.x == 0 && threadIdx.x == 0) {
      #pragma unroll
      for (int e = 0; e < NE; ++e) offs_out[e] = offl[e];
      offs_out[NE] = o;
    }
  }
  int t = blockIdx.x * 256 + threadIdx.x;
  int lane = threadIdx.x & 63;
  #pragma unroll
  for (int k = 0; k < 2; ++k) {
    int e = sel_e[2 * t + k];
    float w = sel_w[2 * t + k];
    for (int xch = 0; xch < NE; ++xch) {
      unsigned long long m = __ballot(e == xch);
      if (e == xch) {
        int leader = __ffsll((unsigned long long)m) - 1;
        int base = 0;
        if (lane == leader) base = atomicAdd(&cursor[xch], (int)__popcll(m));
        base = __shfl(base, leader);
        int pos = offl[xch] + base + (int)__popcll(m & ((1ull << lane) - 1));
        rowtok[pos] = t;
        rowcoef[pos] = w;
        inv[2 * t + k] = pos;
      }
    }
  }
}

// ---------------------------------------------------------------------------
// Gather: xg[row] = fp16(x[rowtok[row]]); zeros for padding rows (tok = -1).
// ---------------------------------------------------------------------------
__global__ __launch_bounds__(256) void gather_kernel(
    const float* __restrict__ x, const int* __restrict__ rowtok,
    _Float16* __restrict__ xg)
{
  int r = blockIdx.x;
  int tok = rowtok[r];
  int t4 = threadIdx.x * 4;
  _Float16* dst = xg + (size_t)r * EMBED + t4;
  if (tok >= 0) {
    float4 v = *(const float4*)(x + (size_t)tok * EMBED + t4);
    f16x4 h; h.x = (_Float16)v.x; h.y = (_Float16)v.y; h.z = (_Float16)v.z; h.w = (_Float16)v.w;
    *(f16x4*)dst = h;
  } else {
    f16x4 z = {(_Float16)0.f, (_Float16)0.f, (_Float16)0.f, (_Float16)0.f};
    *(f16x4*)dst = z;
  }
}

// ---------------------------------------------------------------------------
// Transpose+cast all three weight tensors in ONE launch.
// fp32 [E][K][N] -> fp16 [E][N][K]. 512 64x64 tiles per (matrix, expert).
// ---------------------------------------------------------------------------
__global__ __launch_bounds__(256) void transpose_all_kernel(
    const float* __restrict__ w1, const float* __restrict__ w3,
    const float* __restrict__ w2, _Float16* __restrict__ w1t,
    _Float16* __restrict__ w3t, _Float16* __restrict__ w2t)
{
  int id = blockIdx.x;            // 3 * 8 * 512
  int mat = id >> 12;             // 4096 blocks per matrix
  int rr = id & 4095;
  int e = rr >> 9, tile = rr & 511;
  const float* src; _Float16* dst; int K, N;
  if (mat == 0)      { src = w1; dst = w1t; K = EMBED; N = MLP; }
  else if (mat == 1) { src = w3; dst = w3t; K = EMBED; N = MLP; }
  else               { src = w2; dst = w2t; K = MLP;   N = EMBED; }
  int nx = K >> 6;
  int k0 = (tile % nx) * 64, n0 = (tile / nx) * 64;
  src += (size_t)e * K * N;
  dst += (size_t)e * K * N;

  __shared__ float tilebuf[64][65];
  int t = threadIdx.x;
  int r = t >> 4, c4 = (t & 15) * 4;
  #pragma unroll
  for (int i = 0; i < 4; ++i) {
    float4 v = *(const float4*)(src + (size_t)(k0 + r + 16 * i) * N + n0 + c4);
    tilebuf[r + 16 * i][c4 + 0] = v.x;
    tilebuf[r + 16 * i][c4 + 1] = v.y;
    tilebuf[r + 16 * i][c4 + 2] = v.z;
    tilebuf[r + 16 * i][c4 + 3] = v.w;
  }
  __syncthreads();
  int kk8 = (t & 7) * 8, nIdx = t >> 3;
  #pragma unroll
  for (int i = 0; i < 2; ++i) {
    int n = nIdx + 32 * i;
    f16x8 h;
    #pragma unroll
    for (int j = 0; j < 8; ++j) h[j] = (_Float16)tilebuf[kk8 + j][n];
    *(f16x8*)(dst + (size_t)(n0 + n) * K + k0 + kk8) = h;
  }
}

// ---------------------------------------------------------------------------
__device__ __forceinline__ int resolve_expert(const int* __restrict__ offs, int r0)
{
  int e = 0;
  #pragma unroll
  for (int q = 0; q < NE - 1; ++q) if (r0 >= offs[q + 1]) e = q + 1;
  return e;
}

// Tile rows x 32 f16 (64 B/row), 4 chunks of 16 B per row.
// Physical slot (row, kqp) holds logical k-quarter kql = kqp ^ ((row>>1)&3)
// (round-2-verified: 0 bank conflicts). Read: phys = quad ^ ((row>>1)&3).
__device__ __forceinline__ const _Float16* frag_addr(const _Float16* buf, int row, int quad)
{
  return buf + row * 32 + ((quad ^ ((row >> 1) & 3)) << 3);
}

// ---------------------------------------------------------------------------
// GEMM1 (fused SwiGLU): h = silu(xg@w1t^T) * (xg@w3t^T) * coef, fp16 out.
// 256x128 tile, 512 threads / 8 waves (wave tile 64x64), BK=32.
// Triple-buffered LDS, raw s_barrier + manual s_waitcnt vmcnt(N) so stage(k+1)
// stays in flight across the barrier. 256-row tile halves staged bytes per
// MFMA vs 128x128 (A amortized over 2x rows): the round-4 L2-bandwidth fix.
// ---------------------------------------------------------------------------
__global__ __launch_bounds__(512, 2) void gemm1_kernel(
    const _Float16* __restrict__ xg, const _Float16* __restrict__ w1t,
    const _Float16* __restrict__ w3t, const float* __restrict__ rowcoef,
    const int* __restrict__ offs, _Float16* __restrict__ hb)
{
  int r0 = blockIdx.x * 256;
  if (r0 >= offs[NE]) return;
  int e = resolve_expert(offs, r0);
  int n0 = blockIdx.y * 128;
  const _Float16* B1 = w1t + (size_t)e * MLP * EMBED;
  const _Float16* B3 = w3t + (size_t)e * MLP * EMBED;

  __shared__ __align__(16) _Float16 As[3][256 * 32];    // 3 x 16 KB
  __shared__ __align__(16) _Float16 Bs1[3][128 * 32];   // 3 x 8 KB
  __shared__ __align__(16) _Float16 Bs3[3][128 * 32];   // 3 x 8 KB

  int tid = threadIdx.x, lane = tid & 63, wv = tid >> 6;  // wv 0..7
  int wm = (wv & 3) << 6, wn = (wv >> 2) << 6;            // 4 m-waves x 2 n-waves
  int l16 = lane & 15, quad = lane >> 4;

  // A: 1024 chunks, 2 per thread (c = tid, tid+512). B: 512 chunks, 1/thread.
  int rowA0 = tid >> 2, kqpA = tid & 3;
  int rowA1 = rowA0 + 128;
  int kqlA0 = kqpA ^ ((rowA0 >> 1) & 3);
  int kqlA1 = kqpA ^ ((rowA1 >> 1) & 3);
  int rowB = tid >> 2, kqpB = tid & 3;
  int kqlB = kqpB ^ ((rowB >> 1) & 3);
  size_t gA0 = (size_t)(r0 + rowA0) * EMBED + kqlA0 * 8;
  size_t gA1 = (size_t)(r0 + rowA1) * EMBED + kqlA1 * 8;
  size_t gB  = (size_t)(n0 + rowB) * EMBED + kqlB * 8;
  int lofA0 = (wv * 64) * 8;          // wave-uniform LDS bases (f16 units)
  int lofA1 = (512 + wv * 64) * 8;
  int lofB  = (wv * 64) * 8;

  f32x4 acc1[4][4], acc3[4][4];
  f32x4 z4 = {0.f, 0.f, 0.f, 0.f};
  #pragma unroll
  for (int i = 0; i < 4; ++i)
    #pragma unroll
    for (int j = 0; j < 4; ++j) { acc1[i][j] = z4; acc3[i][j] = z4; }

  auto stage = [&](int b, int kk) {
    async_copy16(xg + gA0 + kk, &As[b][lofA0]);
    async_copy16(xg + gA1 + kk, &As[b][lofA1]);
    async_copy16(B1 + gB  + kk, &Bs1[b][lofB]);
    async_copy16(B3 + gB  + kk, &Bs3[b][lofB]);
  };

  const int NIT = EMBED / 32;        // 32 iters
  stage(0, 0);
  for (int k = 0; k < NIT; ++k) {
    int b = k % 3;
    if (k + 1 < NIT) {
      stage((k + 1) % 3, (k + 1) * 32);
      asm volatile("s_waitcnt vmcnt(4)" ::: "memory");   // stage(k) drained
    } else {
      asm volatile("s_waitcnt vmcnt(0)" ::: "memory");
    }
    asm volatile("s_barrier" ::: "memory");

    f16x8 af[4], b1f[4], b3f[4];
    #pragma unroll
    for (int i = 0; i < 4; ++i)
      af[i] = *(const f16x8*)frag_addr(As[b], wm + 16 * i + l16, quad);
    #pragma unroll
    for (int j = 0; j < 4; ++j) {
      b1f[j] = *(const f16x8*)frag_addr(Bs1[b], wn + 16 * j + l16, quad);
      b3f[j] = *(const f16x8*)frag_addr(Bs3[b], wn + 16 * j + l16, quad);
    }
    #pragma unroll
    for (int i = 0; i < 4; ++i)
      #pragma unroll
      for (int j = 0; j < 4; ++j) {
        acc1[i][j] = __builtin_amdgcn_mfma_f32_16x16x32_f16(af[i], b1f[j], acc1[i][j], 0, 0, 0);
        acc3[i][j] = __builtin_amdgcn_mfma_f32_16x16x32_f16(af[i], b3f[j], acc3[i][j], 0, 0, 0);
      }
  }

  // Epilogue: h = silu(g)*u*coef[row]; C/D layout col=lane&15, row=quad*4+reg.
  #pragma unroll
  for (int i = 0; i < 4; ++i) {
    int mb = r0 + wm + 16 * i + quad * 4;
    float cf[4];
    #pragma unroll
    for (int rg = 0; rg < 4; ++rg) cf[rg] = rowcoef[mb + rg];
    #pragma unroll
    for (int j = 0; j < 4; ++j) {
      int col = n0 + wn + 16 * j + l16;
      #pragma unroll
      for (int rg = 0; rg < 4; ++rg) {
        float g = acc1[i][j][rg], u = acc3[i][j][rg];
        float h = g * u * cf[rg] / (1.f + __expf(-g));
        hb[(size_t)(mb + rg) * MLP + col] = (_Float16)h;
      }
    }
  }
}

// ---------------------------------------------------------------------------
// GEMM2: hb2[row] = h[row] @ w2t^T, fp16 per-row out (no atomics; combine
// sums the 2 rows per token). 256x128 tile, same pipelined K-loop, K=2048.
// ---------------------------------------------------------------------------
__global__ __launch_bounds__(512, 2) void gemm2_kernel(
    const _Float16* __restrict__ hb, const _Float16* __restrict__ w2t,
    const int* __restrict__ offs, _Float16* __restrict__ hb2)
{
  int r0 = blockIdx.x * 256;
  if (r0 >= offs[NE]) return;
  int e = resolve_expert(offs, r0);
  int n0 = blockIdx.y * 128;
  const _Float16* B = w2t + (size_t)e * EMBED * MLP;

  __shared__ __align__(16) _Float16 As[3][256 * 32];    // 3 x 16 KB
  __shared__ __align__(16) _Float16 Bs[3][128 * 32];    // 3 x 8 KB

  int tid = threadIdx.x, lane = tid & 63, wv = tid >> 6;
  int wm = (wv & 3) << 6, wn = (wv >> 2) << 6;
  int l16 = lane & 15, quad = lane >> 4;

  int rowA0 = tid >> 2, kqpA = tid & 3;
  int rowA1 = rowA0 + 128;
  int kqlA0 = kqpA ^ ((rowA0 >> 1) & 3);
  int kqlA1 = kqpA ^ ((rowA1 >> 1) & 3);
  int rowB = tid >> 2, kqpB = tid & 3;
  int kqlB = kqpB ^ ((rowB >> 1) & 3);
  size_t gA0 = (size_t)(r0 + rowA0) * MLP + kqlA0 * 8;
  size_t gA1 = (size_t)(r0 + rowA1) * MLP + kqlA1 * 8;
  size_t gB  = (size_t)(n0 + rowB) * MLP + kqlB * 8;
  int lofA0 = (wv * 64) * 8;
  int lofA1 = (512 + wv * 64) * 8;
  int lofB  = (wv * 64) * 8;

  f32x4 acc[4][4];
  f32x4 z4 = {0.f, 0.f, 0.f, 0.f};
  #pragma unroll
  for (int i = 0; i < 4; ++i)
    #pragma unroll
    for (int j = 0; j < 4; ++j) acc[i][j] = z4;

  auto stage = [&](int b, int kk) {
    async_copy16(hb + gA0 + kk, &As[b][lofA0]);
    async_copy16(hb + gA1 + kk, &As[b][lofA1]);
    async_copy16(B  + gB  + kk, &Bs[b][lofB]);
  };

  const int NIT = MLP / 32;          // 64 iters
  stage(0, 0);
  for (int k = 0; k < NIT; ++k) {
    int b = k % 3;
    if (k + 1 < NIT) {
      stage((k + 1) % 3, (k + 1) * 32);
      asm volatile("s_waitcnt vmcnt(3)" ::: "memory");
    } else {
      asm volatile("s_waitcnt vmcnt(0)" ::: "memory");
    }
    asm volatile("s_barrier" ::: "memory");

    f16x8 af[4], bf[4];
    #pragma unroll
    for (int i = 0; i < 4; ++i)
      af[i] = *(const f16x8*)frag_addr(As[b], wm + 16 * i + l16, quad);
    #pragma unroll
    for (int j = 0; j < 4; ++j)
      bf[j] = *(const f16x8*)frag_addr(Bs[b], wn + 16 * j + l16, quad);
    #pragma unroll
    for (int i = 0; i < 4; ++i)
      #pragma unroll
      for (int j = 0; j < 4; ++j)
        acc[i][j] = __builtin_amdgcn_mfma_f32_16x16x32_f16(af[i], bf[j], acc[i][j], 0, 0, 0);
  }

  #pragma unroll
  for (int i = 0; i < 4; ++i) {
    int mb = r0 + wm + 16 * i + quad * 4;
    #pragma unroll
    for (int j = 0; j < 4; ++j) {
      int col = n0 + wn + 16 * j + l16;
      #pragma unroll
      for (int rg = 0; rg < 4; ++rg)
        hb2[(size_t)(mb + rg) * EMBED + col] = (_Float16)acc[i][j][rg];
    }
  }
}

// ---------------------------------------------------------------------------
// Combine: out[t] = hb2[inv[2t]] + hb2[inv[2t+1]] (fp32 out).
// ---------------------------------------------------------------------------
__global__ __launch_bounds__(256) void combine_kernel(
    const _Float16* __restrict__ hb2, const int* __restrict__ inv,
    float* __restrict__ out)
{
  int t = blockIdx.x;
  int d = threadIdx.x * 4;
  int p0 = inv[2 * t], p1 = inv[2 * t + 1];
  f16x4 a = *(const f16x4*)(hb2 + (size_t)p0 * EMBED + d);
  f16x4 b = *(const f16x4*)(hb2 + (size_t)p1 * EMBED + d);
  float4 r;
  r.x = (float)a.x + (float)b.x;
  r.y = (float)a.y + (float)b.y;
  r.z = (float)a.z + (float)b.z;
  r.w = (float)a.w + (float)b.w;
  *(float4*)(out + (size_t)t * EMBED + d) = r;
}

// ---------------------------------------------------------------------------
extern "C" void kernel_launch(void* const* d_in, const int* in_sizes, int n_in,
                              void* d_out, int out_size, void* d_ws, size_t ws_size,
                              hipStream_t stream)
{
  (void)in_sizes; (void)n_in; (void)ws_size; (void)out_size;
  const float* x  = (const float*)d_in[0];
  const float* gw = (const float*)d_in[1];
  const float* w1 = (const float*)d_in[2];
  const float* w2 = (const float*)d_in[3];   // NOTE: dict order is w1, w2, w3
  const float* w3 = (const float*)d_in[4];
  float* out = (float*)d_out;
  char* ws = (char*)d_ws;

  size_t o = 0;
  auto alloc = [&](size_t bytes) { size_t r = o; o = (o + bytes + 255) & ~255ULL; return r; };
  const size_t wbytes = (size_t)NE * MLP * EMBED * 2;
  _Float16* w1t = (_Float16*)(ws + alloc(wbytes));
  _Float16* w3t = (_Float16*)(ws + alloc(wbytes));
  _Float16* w2t = (_Float16*)(ws + alloc(wbytes));
  _Float16* xg  = (_Float16*)(ws + alloc((size_t)RMAX * EMBED * 2));
  _Float16* hb  = (_Float16*)(ws + alloc((size_t)RMAX * MLP * 2));
  int*   rowtok  = (int*)(ws + alloc((size_t)RMAX * 4));
  float* rowcoef = (float*)(ws + alloc((size_t)RMAX * 4));
  int*   sel_e   = (int*)(ws + alloc((size_t)2 * NTOK * 4));
  float* sel_w   = (float*)(ws + alloc((size_t)2 * NTOK * 4));
  int*   inv     = (int*)(ws + alloc((size_t)2 * NTOK * 4));
  int*   meta    = (int*)(ws + alloc(256));
  int* counts = meta;          // [8]
  int* offs   = meta + 8;      // [9]
  int* cursor = meta + 17;     // [8] (zero-based)
  // hb2 aliases xg: xg is dead after gemm1; both are RMAX*EMBED fp16.
  _Float16* hb2 = xg;

  hipMemsetAsync(meta, 0, 256, stream);
  hipMemsetAsync(rowtok, 0xFF, (size_t)RMAX * 4, stream);   // -1 = padding
  hipMemsetAsync(rowcoef, 0, (size_t)RMAX * 4, stream);

  transpose_all_kernel<<<3 * 4096, 256, 0, stream>>>(w1, w3, w2, w1t, w3t, w2t);

  router_kernel<<<NTOK / 4, 256, 0, stream>>>(x, gw, sel_e, sel_w, counts);
  assign_kernel<<<NTOK / 256, 256, 0, stream>>>(sel_e, sel_w, counts, cursor,
                                                offs, rowtok, rowcoef, inv);
  gather_kernel<<<RMAX, 256, 0, stream>>>(x, rowtok, xg);

  gemm1_kernel<<<dim3(RMAX / 256, MLP / 128), 512, 0, stream>>>(xg, w1t, w3t, rowcoef, offs, hb);
  gemm2_kernel<<<dim3(RMAX / 256, EMBED / 128), 512, 0, stream>>>(hb, w2t, offs, hb2);
  combine_kernel<<<NTOK, 256, 0, stream>>>(hb2, inv, out);
}